// Round 4
// baseline (173.611 us; speedup 1.0000x reference)
//
#include <hip/hip_runtime.h>

typedef _Float16 f16x8 __attribute__((ext_vector_type(8)));
typedef _Float16 f16x4 __attribute__((ext_vector_type(4)));
typedef short s16x4 __attribute__((ext_vector_type(4)));
typedef float f32x4 __attribute__((ext_vector_type(4)));

#define MFMA_K32(a, b, c) __builtin_amdgcn_mfma_f32_16x16x32_f16(a, b, c, 0, 0, 0)
#define MFMA_BF(a, b, c)  __builtin_amdgcn_mfma_f32_16x16x16bf16_1k(a, b, c, 0, 0, 0)
#define MFMA_F16(a, b, c) __builtin_amdgcn_mfma_f32_16x16x16f16(a, b, c, 0, 0, 0)

// B=8, N=3136, C=256, Ci=128, M=1568, NT=25088 rows. I/O fp32.
// Fragment-major internals (every hot load = base + lane*16B):
//   theta_f [1568 tiles][kc 4][lane 64][8]          (f16)
//   phi_f [8][chunk 49][kvt 2][kc 4][lane 64][8]    (f16)
//   g_f   [8][chunk 49][ct 8][lane 64][half 2][4]   (bf16) == V A-frag
//   wt_f  [3][ct 8][kc 8][lane 64][8]               (f16)
//   wfT_f [ctile 16][lane 64][kc2 8][4]             (f16) == w_final^T A-frag
// Softmax: static-shift (no online max): p = exp2(s*log2e - 104), P/V bf16.
// ROUND-4: finer-grain decomposition for occupancy.
//  k_proj: unit = (tile, w-matrix) -> 4704 waves @ ~100 VGPR (4/SIMD).
//  k_attn: m=2 tiles/wave, kv-split 4 -> grid 784, 3136 waves; lower VGPR
//  (o 64 + qf 32) lets the reg-dbuf prefetch schedule without forced waits;
//  2 blocks (8 waves) resident/CU uniformly. Combine tree 32KB LDS; fused
//  w_final epilogue split over (tile, ctile-half) per wave.

__device__ __forceinline__ f16x8 ld8f(const float* __restrict__ p) {
    f32x4 a = *(const f32x4*)p;
    f32x4 b = *(const f32x4*)(p + 4);
    f16x8 r;
    r[0] = (_Float16)a[0]; r[1] = (_Float16)a[1];
    r[2] = (_Float16)a[2]; r[3] = (_Float16)a[3];
    r[4] = (_Float16)b[0]; r[5] = (_Float16)b[1];
    r[6] = (_Float16)b[2]; r[7] = (_Float16)b[3];
    return r;
}
__device__ __forceinline__ unsigned f2bf_rne(float f) {
    unsigned u = __float_as_uint(f);
    return (u + 0x7FFFu + ((u >> 16) & 1u)) >> 16;
}
__device__ __forceinline__ int bfpack_rtz(float lo, float hi) {
    return (int)((__float_as_uint(hi) & 0xFFFF0000u) | (__float_as_uint(lo) >> 16));
}

// ---------------------------------------------------------------------------
// Prep: weights fp32 -> f16, fragment-major.  grid 512, block 256.
// wfT: A-frag of w_final^T: value wf[Ci=kc2*16+q*4+jj][col=ct*16+t]
//      at [ct*2048 + lane*32 + kc2*4 + jj].
// ---------------------------------------------------------------------------
__global__ void k_prep(const float* __restrict__ wt, const float* __restrict__ wp,
                       const float* __restrict__ wg, const float* __restrict__ wf,
                       _Float16* __restrict__ wt_f, _Float16* __restrict__ wfT_f) {
    int i = blockIdx.x * 256 + threadIdx.x;  // 0..131071
    int w = i >> 15, idx = i & 32767;
    if (w < 3) {
        const float* src = (w == 0) ? wt : (w == 1) ? wp : wg;
        int k = idx >> 7, n = idx & 127;
        int ct = n >> 4, tt = n & 15, kc = k >> 5, qq = (k >> 3) & 3, jj = k & 7;
        wt_f[((w * 8 + ct) * 8 + kc) * 512 + (qq * 16 + tt) * 8 + jj] = (_Float16)src[idx];
    } else {
        int k = idx >> 8, n = idx & 255;        // k = Ci 0..127, n = out col 0..255
        int ct = n >> 4, tt = n & 15;
        int kc2 = k >> 4, qq = (k >> 2) & 3, jj = k & 3;
        wfT_f[ct * 2048 + (qq * 16 + tt) * 32 + kc2 * 4 + jj] = (_Float16)wf[idx];
    }
}

// ---------------------------------------------------------------------------
// Projections, one (tile, weight-matrix) unit per wave; maxpool(2) fused.
// grid 1176, block 256 (4 waves).  4704 units = 1568 tiles x 3 matrices.
// ---------------------------------------------------------------------------
__global__ __launch_bounds__(256) void k_proj(
    const float* __restrict__ x,        // [25088][256] fp32
    const _Float16* __restrict__ wt_f,  // [3][8][8][512]
    _Float16* __restrict__ theta_f,     // [1568][2048]
    _Float16* __restrict__ phi_f,       // [8][49][4096]
    short* __restrict__ g_f)            // [8][49][4096] bf16
{
    const int u    = blockIdx.x * 4 + (threadIdx.x >> 6);  // 0..4703
    const int lane = threadIdx.x & 63;
    const int q = lane >> 4, t = lane & 15;

    const int tt = u / 3;            // tile 0..1567
    const int w  = u - tt * 3;       // 0=theta 1=phi 2=g

    const int mrow = tt * 16 + t;
    f16x8 af[8];
#pragma unroll
    for (int kc = 0; kc < 8; ++kc)
        af[kc] = ld8f(x + mrow * 256 + kc * 32 + q * 8);

    const f32x4 zero = {0.f, 0.f, 0.f, 0.f};
    f32x4 acc[8];
#pragma unroll
    for (int ct = 0; ct < 8; ++ct) acc[ct] = zero;

#pragma unroll
    for (int ct = 0; ct < 8; ++ct) {
        const _Float16* Wc = wt_f + ((w * 8 + ct) * 8) * 512 + lane * 8;
#pragma unroll
        for (int kc = 0; kc < 8; ++kc)
            acc[ct] = MFMA_K32(af[kc], *(const f16x8*)(Wc + kc * 512), acc[ct]);
    }

    if (w == 0) {
        // theta -> fragment-major tile
        _Float16* tb = theta_f + tt * 2048;
#pragma unroll
        for (int ct = 0; ct < 8; ++ct) {
            const int off = (ct >> 1) * 512 + ((ct & 1) * 2 + (t >> 3)) * 128 + (t & 7);
#pragma unroll
            for (int r = 0; r < 4; ++r)
                tb[off + (q * 4 + r) * 8] = (_Float16)acc[ct][r];
        }
        return;
    }

    const int b     = tt / 196;
    const int tl    = tt - b * 196;      // local tile 0..195
    const int chunk = tl >> 2;           // 0..48
    const int sub   = tl & 3;            // 2 tiles per h-half
    const int h     = sub >> 1;          // kvt bit

    if (w == 1) {
        const int ttp = (sub & 1) * 8 + q * 2;   // pooled row & 15 (even)
        _Float16* pcb = phi_f + (b * 49 + chunk) * 4096;
#pragma unroll
        for (int ct = 0; ct < 8; ++ct) {
            const int kc = ct >> 1;
            const int qq = (ct & 1) * 2 + (t >> 3);
            const int j  = t & 7;
            const int off = (h * 4 + kc) * 512 + (qq * 16 + ttp) * 8 + j;
            pcb[off]     = (_Float16)fmaxf(acc[ct][0], acc[ct][1]);
            pcb[off + 8] = (_Float16)fmaxf(acc[ct][2], acc[ct][3]);
        }
    } else {
        // g: V A-frag: lane = qv*16 + ci15, j8 = h*4 + (kv'&3)
        short* gcb = g_f + (b * 49 + chunk) * 4096;
        const int qv  = (sub & 1) * 2 + (q >> 1);
        const int jj0 = (q & 1) * 2;
#pragma unroll
        for (int ct = 0; ct < 8; ++ct) {
            unsigned lo = f2bf_rne(fmaxf(acc[ct][0], acc[ct][1]));
            unsigned hi = f2bf_rne(fmaxf(acc[ct][2], acc[ct][3]));
            *(unsigned*)(gcb + ct * 512 + (qv * 16 + t) * 8 + h * 4 + jj0) = lo | (hi << 16);
        }
    }
}

// ---------------------------------------------------------------------------
// Attention + final, fused, split-KV.  grid 784 (8 b x 98), block 256.
// m=2 tiles/wave; wave w scans chunks c ≡ w (mod 4) straight from L2.
// ---------------------------------------------------------------------------
#define LOADKV(DST, SRC) { _Pragma("unroll") \
    for (int j = 0; j < 8; ++j) DST[j] = *(const f16x8*)((SRC) + j * 512 + lane * 8); }

#define QKSM(PH) { \
    f32x4 st0[2], st1[2]; \
    _Pragma("unroll") for (int m = 0; m < 2; ++m) { st0[m] = zero; st1[m] = zero; } \
    __builtin_amdgcn_s_setprio(1); \
    _Pragma("unroll") for (int kc = 0; kc < 4; ++kc) \
      _Pragma("unroll") for (int m = 0; m < 2; ++m) { \
        st0[m] = MFMA_K32(PH[kc],     qf[m][kc], st0[m]); \
        st1[m] = MFMA_K32(PH[4 + kc], qf[m][kc], st1[m]); } \
    __builtin_amdgcn_s_setprio(0); \
    _Pragma("unroll") for (int m = 0; m < 2; ++m) { \
      f32x4 p0, p1; \
      _Pragma("unroll") for (int r = 0; r < 4; ++r) { \
        p0[r] = exp2f(st0[m][r] * L2E - SHIFT); \
        p1[r] = exp2f(st1[m][r] * L2E - SHIFT); } \
      lsum[m] += ((p0[0] + p0[1]) + (p0[2] + p0[3])) \
               + ((p1[0] + p1[1]) + (p1[2] + p1[3])); \
      u[m][0].i2[0] = bfpack_rtz(p0[0], p0[1]); \
      u[m][0].i2[1] = bfpack_rtz(p0[2], p0[3]); \
      u[m][1].i2[0] = bfpack_rtz(p1[0], p1[1]); \
      u[m][1].i2[1] = bfpack_rtz(p1[2], p1[3]); } }

// swapped operands: A = V (g frag), B = P  -> o'[Ci][qrow] (transposed)
#define PV(AG) { \
    __builtin_amdgcn_s_setprio(1); \
    _Pragma("unroll") for (int ct = 0; ct < 8; ++ct) { \
      union { f16x8 f; s16x4 s[2]; } uv; uv.f = AG[ct]; \
      _Pragma("unroll") for (int m = 0; m < 2; ++m) { \
        o[m][ct] = MFMA_BF(uv.s[0], u[m][0].v, o[m][ct]); \
        o[m][ct] = MFMA_BF(uv.s[1], u[m][1].v, o[m][ct]); } } \
    __builtin_amdgcn_s_setprio(0); }

__global__ __launch_bounds__(256) void k_attn(
    const _Float16* __restrict__ theta_f,  // [1568][2048]
    const _Float16* __restrict__ phi_f,    // [8][49][4096]
    const short* __restrict__ g_f,         // [8][49][4096] bf16
    const _Float16* __restrict__ wfT_f,    // [16][64][8][4]
    const float* __restrict__ x,           // [25088][256]
    float* __restrict__ out)               // [25088][256]
{
    const int blk  = blockIdx.x;          // 784 = 8 batches x 98
    const int b    = blk & 7;             // XCD affinity
    const int blkm = blk >> 3;            // 0..97
    const int wave = threadIdx.x >> 6;
    const int lane = threadIdx.x & 63;
    const int q = lane >> 4, t = lane & 15;

    __shared__ __align__(16) float cbuf[2][4096];  // 32 KB
    __shared__ float lbuf[2][128];                 //  1 KB

    const int tIdx0 = b * 196 + blkm * 2;           // 2 consecutive m-tiles
    const _Float16* ph = phi_f + b * 200704;
    const _Float16* gt = (const _Float16*)(g_f + b * 200704);

    // Q fragments: 2 tiles x 4 kc, register-resident for the whole scan
    f16x8 qf[2][4];
#pragma unroll
    for (int m = 0; m < 2; ++m)
#pragma unroll
        for (int kc = 0; kc < 4; ++kc)
            qf[m][kc] = *(const f16x8*)(theta_f + (tIdx0 + m) * 2048 + kc * 512 + lane * 8);

    const f32x4 zero = {0.f, 0.f, 0.f, 0.f};
    f32x4 o[2][8];
#pragma unroll
    for (int m = 0; m < 2; ++m)
#pragma unroll
        for (int ct = 0; ct < 8; ++ct) o[m][ct] = zero;
    float lsum[2] = {0.f, 0.f};
    union ubf { int i2[2]; s16x4 v; } u[2][2];
    const float L2E = 1.44269504f, SHIFT = 104.0f;

    // wave w scans chunks c ≡ w (mod 4): 12 chunks each + chunk 48 on wave 0
    f16x8 phA[8], phB[8], ag[8];
    int c = wave;
    LOADKV(phA, ph + c * 4096);

#pragma unroll 1
    for (int k = 0; k < 6; ++k) {            // covers c, c+4 for c = wave+8k
        LOADKV(ag, gt + c * 4096);
        QKSM(phA);                           // chunk c
        LOADKV(phB, ph + (c + 4) * 4096);    // prefetch under PV
        PV(ag);
        LOADKV(ag, gt + (c + 4) * 4096);
        QKSM(phB);                           // chunk c+4
        if (c + 8 <= 48) LOADKV(phA, ph + (c + 8) * 4096);  // uniform branch
        PV(ag);
        c += 8;
    }
    if (wave == 0) {                         // tail: chunk 48 (phA holds it)
        LOADKV(ag, gt + 48 * 4096);
        QKSM(phA);
        PV(ag);
    }

    // ---- cross-wave combine: static shift => partials simply add ----
    if (wave >= 2) {
        float* cb = cbuf[wave - 2];
#pragma unroll
        for (int m = 0; m < 2; ++m) {
#pragma unroll
            for (int ct = 0; ct < 8; ++ct)
                *(f32x4*)&cb[(m * 8 + ct) * 256 + lane * 4] = o[m][ct];
            lbuf[wave - 2][m * 64 + lane] = lsum[m];
        }
    }
    __syncthreads();
    if (wave < 2) {                          // 0 += wave2, 1 += wave3
        const float* cb = cbuf[wave];
#pragma unroll
        for (int m = 0; m < 2; ++m) {
#pragma unroll
            for (int ct = 0; ct < 8; ++ct)
                o[m][ct] += *(const f32x4*)&cb[(m * 8 + ct) * 256 + lane * 4];
            lsum[m] += lbuf[wave][m * 64 + lane];
        }
    }
    __syncthreads();
    if (wave == 1) {
        float* cb = cbuf[0];
#pragma unroll
        for (int m = 0; m < 2; ++m) {
#pragma unroll
            for (int ct = 0; ct < 8; ++ct)
                *(f32x4*)&cb[(m * 8 + ct) * 256 + lane * 4] = o[m][ct];
            lbuf[0][m * 64 + lane] = lsum[m];
        }
    }
    __syncthreads();
    if (wave == 0) {
        const float* cb = cbuf[0];
#pragma unroll
        for (int m = 0; m < 2; ++m) {
#pragma unroll
            for (int ct = 0; ct < 8; ++ct)
                o[m][ct] += *(const f32x4*)&cb[(m * 8 + ct) * 256 + lane * 4];
            lsum[m] += lbuf[0][m * 64 + lane];
        }
        // publish final per-tile: cbuf[m][ct*256 + lane*4], lbuf[m][lane]
#pragma unroll
        for (int m = 0; m < 2; ++m) {
#pragma unroll
            for (int ct = 0; ct < 8; ++ct)
                *(f32x4*)&cbuf[m][ct * 256 + lane * 4] = o[m][ct];
            lbuf[m][lane] = lsum[m];
        }
    }
    __syncthreads();

    // epilogue split: wave -> tile (wave&1), ctile half (wave>>1)
    const int mt = wave & 1;
    f32x4 ow[8];
#pragma unroll
    for (int ct = 0; ct < 8; ++ct)
        ow[ct] = *(const f32x4*)&cbuf[mt][ct * 256 + lane * 4];
    float lf = lbuf[mt][lane];
    lf += __shfl_xor(lf, 16);
    lf += __shfl_xor(lf, 32);
    const float inv = 1.0f / lf;

    // ow[ct][r] = y[row t][Ci = ct*16+4q+r] -> exactly the K16 B-frag
    f16x4 yf[8];
#pragma unroll
    for (int ct = 0; ct < 8; ++ct)
#pragma unroll
        for (int r = 0; r < 4; ++r)
            yf[ct][r] = (_Float16)(ow[ct][r] * inv);

    // fused final for tile (tIdx0+mt): out = x + y @ w_final
    const int row = (tIdx0 + mt) * 16 + t;
    const int c0  = (wave >> 1) * 8;
#pragma unroll 1
    for (int ci = 0; ci < 8; ++ci) {
        const int ctile = c0 + ci;
        union { f16x8 v8; f16x4 v4[2]; } w[4];
#pragma unroll
        for (int p = 0; p < 4; ++p)
            w[p].v8 = *(const f16x8*)(wfT_f + ctile * 2048 + lane * 32 + p * 8);
        f32x4 acc = zero;
#pragma unroll
        for (int kc2 = 0; kc2 < 8; ++kc2)
            acc = MFMA_F16(w[kc2 >> 1].v4[kc2 & 1], yf[kc2], acc);
        const int col = ctile * 16 + q * 4;
        f32x4 xv = *(const f32x4*)(x + row * 256 + col);
        *(f32x4*)(out + row * 256 + col) = acc + xv;
    }
}

// ---------------------------------------------------------------------------
extern "C" void kernel_launch(void* const* d_in, const int* in_sizes, int n_in,
                              void* d_out, int out_size, void* d_ws, size_t ws_size,
                              hipStream_t stream) {
    const float* x  = (const float*)d_in[0];
    const float* wt = (const float*)d_in[1];
    const float* wp = (const float*)d_in[2];
    const float* wg = (const float*)d_in[3];
    const float* wf = (const float*)d_in[4];
    float* out = (float*)d_out;

    _Float16* ws      = (_Float16*)d_ws;
    _Float16* wt_f    = ws;               //  98304
    _Float16* wfT_f   = ws + 98304;       //  32768
    _Float16* theta_f = ws + 131072;      //  3211264
    _Float16* phi_f   = ws + 3342336;     //  1605632
    short*    g_f     = (short*)(ws + 4947968);  // 1605632
    // total 6553600 halves = ~13.1 MB

    k_prep<<<dim3(512),  256, 0, stream>>>(wt, wp, wg, wf, wt_f, wfT_f);
    k_proj<<<dim3(1176), 256, 0, stream>>>(x, wt_f, theta_f, phi_f, g_f);
    k_attn<<<dim3(784),  256, 0, stream>>>(theta_f, phi_f, g_f, wfT_f, x, out);
}

// Round 5
// 160.414 us; speedup vs baseline: 1.0823x; 1.0823x over previous
//
#include <hip/hip_runtime.h>

typedef _Float16 f16x8 __attribute__((ext_vector_type(8)));
typedef _Float16 f16x4 __attribute__((ext_vector_type(4)));
typedef short s16x4 __attribute__((ext_vector_type(4)));
typedef float f32x4 __attribute__((ext_vector_type(4)));

#define MFMA_K32(a, b, c) __builtin_amdgcn_mfma_f32_16x16x32_f16(a, b, c, 0, 0, 0)
#define MFMA_BF(a, b, c)  __builtin_amdgcn_mfma_f32_16x16x16bf16_1k(a, b, c, 0, 0, 0)
#define MFMA_F16(a, b, c) __builtin_amdgcn_mfma_f32_16x16x16f16(a, b, c, 0, 0, 0)

// B=8, N=3136, C=256, Ci=128, M=1568, NT=25088 rows. I/O fp32.
// Fragment-major internals (every hot load = base + lane*16B):
//   theta_f [1568 tiles][kc 4][lane 64][8]          (f16)
//   phi_f [8][chunk 49][kvt 2][kc 4][lane 64][8]    (f16)
//   g_f   [8][chunk 49][ct 8][lane 64][half 2][4]   (bf16) == V A-frag
//   wt_f  [3][ct 8][kc 8][lane 64][8]               (f16)
//   wfT_f [ctile 16][lane 64][kc2 8][4]             (f16) == w_final^T A-frag
// Softmax: static-shift (no online max): p = exp2(s*log2e - 104), P/V bf16.
// ROUND-5: consolidation of measured-best pieces.
//  k_attn: round-0 LDS-staged loop (53.6us measured; direct-L2 variants
//  r1-r4 were latency-bound at 74-93us) + swapped PV (A=V,B=P; o' lands
//  transposed, per-lane 1/l) + fused w_final epilogue -> k_final and the
//  y_f round-trip eliminated.  No setprio (lockstep waves; m190 null).
//  k_proj: round-4 (tile,matrix)-per-wave split for occupancy.

__device__ __forceinline__ f16x8 ld8f(const float* __restrict__ p) {
    f32x4 a = *(const f32x4*)p;
    f32x4 b = *(const f32x4*)(p + 4);
    f16x8 r;
    r[0] = (_Float16)a[0]; r[1] = (_Float16)a[1];
    r[2] = (_Float16)a[2]; r[3] = (_Float16)a[3];
    r[4] = (_Float16)b[0]; r[5] = (_Float16)b[1];
    r[6] = (_Float16)b[2]; r[7] = (_Float16)b[3];
    return r;
}
__device__ __forceinline__ unsigned f2bf_rne(float f) {
    unsigned u = __float_as_uint(f);
    return (u + 0x7FFFu + ((u >> 16) & 1u)) >> 16;
}
__device__ __forceinline__ int bfpack_rtz(float lo, float hi) {
    return (int)((__float_as_uint(hi) & 0xFFFF0000u) | (__float_as_uint(lo) >> 16));
}

// ---------------------------------------------------------------------------
// Prep: weights fp32 -> f16, fragment-major.  grid 512, block 256.
// wfT: A-frag of w_final^T: value wf[Ci=kc2*16+q*4+jj][col=ct*16+t]
//      at [ct*2048 + lane*32 + kc2*4 + jj].
// ---------------------------------------------------------------------------
__global__ void k_prep(const float* __restrict__ wt, const float* __restrict__ wp,
                       const float* __restrict__ wg, const float* __restrict__ wf,
                       _Float16* __restrict__ wt_f, _Float16* __restrict__ wfT_f) {
    int i = blockIdx.x * 256 + threadIdx.x;  // 0..131071
    int w = i >> 15, idx = i & 32767;
    if (w < 3) {
        const float* src = (w == 0) ? wt : (w == 1) ? wp : wg;
        int k = idx >> 7, n = idx & 127;
        int ct = n >> 4, tt = n & 15, kc = k >> 5, qq = (k >> 3) & 3, jj = k & 7;
        wt_f[((w * 8 + ct) * 8 + kc) * 512 + (qq * 16 + tt) * 8 + jj] = (_Float16)src[idx];
    } else {
        int k = idx >> 8, n = idx & 255;        // k = Ci 0..127, n = out col 0..255
        int ct = n >> 4, tt = n & 15;
        int kc2 = k >> 4, qq = (k >> 2) & 3, jj = k & 3;
        wfT_f[ct * 2048 + (qq * 16 + tt) * 32 + kc2 * 4 + jj] = (_Float16)wf[idx];
    }
}

// ---------------------------------------------------------------------------
// Projections, one (tile, weight-matrix) unit per wave; maxpool(2) fused.
// grid 1176, block 256 (4 waves).  4704 units = 1568 tiles x 3 matrices.
// ---------------------------------------------------------------------------
__global__ __launch_bounds__(256) void k_proj(
    const float* __restrict__ x,        // [25088][256] fp32
    const _Float16* __restrict__ wt_f,  // [3][8][8][512]
    _Float16* __restrict__ theta_f,     // [1568][2048]
    _Float16* __restrict__ phi_f,       // [8][49][4096]
    short* __restrict__ g_f)            // [8][49][4096] bf16
{
    const int u    = blockIdx.x * 4 + (threadIdx.x >> 6);  // 0..4703
    const int lane = threadIdx.x & 63;
    const int q = lane >> 4, t = lane & 15;

    const int tt = u / 3;            // tile 0..1567
    const int w  = u - tt * 3;       // 0=theta 1=phi 2=g

    const int mrow = tt * 16 + t;
    f16x8 af[8];
#pragma unroll
    for (int kc = 0; kc < 8; ++kc)
        af[kc] = ld8f(x + mrow * 256 + kc * 32 + q * 8);

    const f32x4 zero = {0.f, 0.f, 0.f, 0.f};
    f32x4 acc[8];
#pragma unroll
    for (int ct = 0; ct < 8; ++ct) acc[ct] = zero;

#pragma unroll
    for (int ct = 0; ct < 8; ++ct) {
        const _Float16* Wc = wt_f + ((w * 8 + ct) * 8) * 512 + lane * 8;
#pragma unroll
        for (int kc = 0; kc < 8; ++kc)
            acc[ct] = MFMA_K32(af[kc], *(const f16x8*)(Wc + kc * 512), acc[ct]);
    }

    if (w == 0) {
        // theta -> fragment-major tile
        _Float16* tb = theta_f + tt * 2048;
#pragma unroll
        for (int ct = 0; ct < 8; ++ct) {
            const int off = (ct >> 1) * 512 + ((ct & 1) * 2 + (t >> 3)) * 128 + (t & 7);
#pragma unroll
            for (int r = 0; r < 4; ++r)
                tb[off + (q * 4 + r) * 8] = (_Float16)acc[ct][r];
        }
        return;
    }

    const int b     = tt / 196;
    const int tl    = tt - b * 196;      // local tile 0..195
    const int chunk = tl >> 2;           // 0..48
    const int sub   = tl & 3;            // 2 tiles per h-half
    const int h     = sub >> 1;          // kvt bit

    if (w == 1) {
        const int ttp = (sub & 1) * 8 + q * 2;   // pooled row & 15 (even)
        _Float16* pcb = phi_f + (b * 49 + chunk) * 4096;
#pragma unroll
        for (int ct = 0; ct < 8; ++ct) {
            const int kc = ct >> 1;
            const int qq = (ct & 1) * 2 + (t >> 3);
            const int j  = t & 7;
            const int off = (h * 4 + kc) * 512 + (qq * 16 + ttp) * 8 + j;
            pcb[off]     = (_Float16)fmaxf(acc[ct][0], acc[ct][1]);
            pcb[off + 8] = (_Float16)fmaxf(acc[ct][2], acc[ct][3]);
        }
    } else {
        // g: V A-frag: lane = qv*16 + ci15, j8 = h*4 + (kv'&3)
        short* gcb = g_f + (b * 49 + chunk) * 4096;
        const int qv  = (sub & 1) * 2 + (q >> 1);
        const int jj0 = (q & 1) * 2;
#pragma unroll
        for (int ct = 0; ct < 8; ++ct) {
            unsigned lo = f2bf_rne(fmaxf(acc[ct][0], acc[ct][1]));
            unsigned hi = f2bf_rne(fmaxf(acc[ct][2], acc[ct][3]));
            *(unsigned*)(gcb + ct * 512 + (qv * 16 + t) * 8 + h * 4 + jj0) = lo | (hi << 16);
        }
    }
}

// ---------------------------------------------------------------------------
// Attention + fused w_final epilogue.  Round-0 LDS-staged structure:
// block = 64 Q rows (wave w owns m-tile w), KV chunk staged in double-
// buffered LDS shared by all 4 waves; prefetch(i+1) overlaps compute(i);
// one barrier per chunk.  PV swapped (A=V,B=P) -> o' transposed ->
// per-lane 1/l -> direct K16 w_final epilogue + x add + out store.
// grid 392 (8 batches x 49 blocks), block 256.
// ---------------------------------------------------------------------------
__global__ __launch_bounds__(256) void k_attn(
    const _Float16* __restrict__ theta_f,  // [1568][2048]
    const _Float16* __restrict__ phi_f,    // [8][49][4096]
    const short* __restrict__ g_f,         // [8][49][4096] bf16
    const _Float16* __restrict__ wfT_f,    // [16][64][8][4]
    const float* __restrict__ x,           // [25088][256]
    float* __restrict__ out)               // [25088][256]
{
    const int blk  = blockIdx.x;          // 392 = 8 batches x 49
    const int b    = blk & 7;             // XCD affinity
    const int blkm = blk >> 3;            // 0..48
    const int wave = threadIdx.x >> 6;
    const int lane = threadIdx.x & 63;
    const int q = lane >> 4, t = lane & 15;

    __shared__ __align__(16) _Float16 kv[2][8192];  // 32 KB: [phi 4096 | g 4096]

    const int tIdx = b * 196 + blkm * 4 + wave;     // this wave's m-tile
    const _Float16* ph = phi_f + b * 200704;
    const _Float16* gt = (const _Float16*)(g_f + b * 200704);

    // Q fragments, coalesced, register-resident for the whole scan
    f16x8 qf[4];
#pragma unroll
    for (int kc = 0; kc < 4; ++kc)
        qf[kc] = *(const f16x8*)(theta_f + tIdx * 2048 + kc * 512 + lane * 8);

    const f32x4 zero = {0.f, 0.f, 0.f, 0.f};
    f32x4 o[8];
#pragma unroll
    for (int ct = 0; ct < 8; ++ct) o[ct] = zero;
    float lsum = 0.f;
    const float L2E = 1.44269504f, SHIFT = 104.0f;

    // staging: wave w copies bytes [w*4KB, (w+1)*4KB) of the 16KB chunk
    const _Float16* src0 = (wave < 2) ? (ph + wave * 2048) : (gt + (wave - 2) * 2048);
    const int doff = wave * 2048;

    f16x8 sr[4];
#pragma unroll
    for (int j = 0; j < 4; ++j)
        sr[j] = *(const f16x8*)(src0 + j * 512 + lane * 8);
#pragma unroll
    for (int j = 0; j < 4; ++j)
        *(f16x8*)(&kv[0][doff + j * 512 + lane * 8]) = sr[j];
    __syncthreads();

    for (int i = 0; i < 49; ++i) {
        if (i + 1 < 49) {
            const _Float16* s = src0 + (i + 1) * 4096;
#pragma unroll
            for (int j = 0; j < 4; ++j)
                sr[j] = *(const f16x8*)(s + j * 512 + lane * 8);
        }

        const _Float16* buf = &kv[i & 1][0];
        // S^T = phi @ theta^T (KV on C rows -> per-lane softmax axis)
        f32x4 st0 = zero, st1 = zero;
#pragma unroll
        for (int kc = 0; kc < 4; ++kc) {
            f16x8 a0 = *(const f16x8*)(buf + kc * 512 + lane * 8);
            f16x8 a1 = *(const f16x8*)(buf + (4 + kc) * 512 + lane * 8);
            st0 = MFMA_K32(a0, qf[kc], st0);
            st1 = MFMA_K32(a1, qf[kc], st1);
        }

        // p = exp2(s*log2e - SHIFT), accumulate l, pack P to bf16
        f32x4 p0, p1;
#pragma unroll
        for (int r = 0; r < 4; ++r) {
            p0[r] = exp2f(st0[r] * L2E - SHIFT);
            p1[r] = exp2f(st1[r] * L2E - SHIFT);
        }
        lsum += ((p0[0] + p0[1]) + (p0[2] + p0[3]))
              + ((p1[0] + p1[1]) + (p1[2] + p1[3]));
        union { int i2[2]; s16x4 v; } u0, u1;
        u0.i2[0] = bfpack_rtz(p0[0], p0[1]);
        u0.i2[1] = bfpack_rtz(p0[2], p0[3]);
        u1.i2[0] = bfpack_rtz(p1[0], p1[1]);
        u1.i2[1] = bfpack_rtz(p1[2], p1[3]);

        // PV swapped: A = V (g frag), B = P -> o'[Ci][qrow] (transposed)
#pragma unroll
        for (int ct = 0; ct < 8; ++ct) {
            union { f16x8 f; s16x4 s[2]; } uv;
            uv.f = *(const f16x8*)(buf + 4096 + ct * 512 + lane * 8);
            o[ct] = MFMA_BF(uv.s[0], u0.v, o[ct]);
            o[ct] = MFMA_BF(uv.s[1], u1.v, o[ct]);
        }

        if (i + 1 < 49) {
            _Float16* d = &kv[(i + 1) & 1][doff];
#pragma unroll
            for (int j = 0; j < 4; ++j)
                *(f16x8*)(d + j * 512 + lane * 8) = sr[j];
        }
        __syncthreads();
    }

    // l per Q-row (row = lane t): reduce across quads; inv per-lane scalar
    float lf = lsum;
    lf += __shfl_xor(lf, 16);
    lf += __shfl_xor(lf, 32);
    const float inv = 1.0f / lf;

    // o[ct][r] = y[row t][Ci = ct*16+4q+r] -> exactly the K16 B-frag
    f16x4 yf[8];
#pragma unroll
    for (int ct = 0; ct < 8; ++ct)
#pragma unroll
        for (int r = 0; r < 4; ++r)
            yf[ct][r] = (_Float16)(o[ct][r] * inv);

    // fused final: out = x + y @ w_final.  D[i=outcol 4q+r][j=row t]
    const int row = tIdx * 16 + t;
#pragma unroll 1
    for (int ctile = 0; ctile < 16; ++ctile) {
        union { f16x8 v8; f16x4 v4[2]; } w[4];
#pragma unroll
        for (int p = 0; p < 4; ++p)
            w[p].v8 = *(const f16x8*)(wfT_f + ctile * 2048 + lane * 32 + p * 8);
        f32x4 acc = zero;
#pragma unroll
        for (int kc2 = 0; kc2 < 8; ++kc2)
            acc = MFMA_F16(w[kc2 >> 1].v4[kc2 & 1], yf[kc2], acc);
        const int col = ctile * 16 + q * 4;
        f32x4 xv = *(const f32x4*)(x + row * 256 + col);
        *(f32x4*)(out + row * 256 + col) = acc + xv;
    }
}

// ---------------------------------------------------------------------------
extern "C" void kernel_launch(void* const* d_in, const int* in_sizes, int n_in,
                              void* d_out, int out_size, void* d_ws, size_t ws_size,
                              hipStream_t stream) {
    const float* x  = (const float*)d_in[0];
    const float* wt = (const float*)d_in[1];
    const float* wp = (const float*)d_in[2];
    const float* wg = (const float*)d_in[3];
    const float* wf = (const float*)d_in[4];
    float* out = (float*)d_out;

    _Float16* ws      = (_Float16*)d_ws;
    _Float16* wt_f    = ws;               //  98304
    _Float16* wfT_f   = ws + 98304;       //  32768
    _Float16* theta_f = ws + 131072;      //  3211264
    _Float16* phi_f   = ws + 3342336;     //  1605632
    short*    g_f     = (short*)(ws + 4947968);  // 1605632
    // total 6553600 halves = ~13.1 MB

    k_prep<<<dim3(512),  256, 0, stream>>>(wt, wp, wg, wf, wt_f, wfT_f);
    k_proj<<<dim3(1176), 256, 0, stream>>>(x, wt_f, theta_f, phi_f, g_f);
    k_attn<<<dim3(392),  256, 0, stream>>>(theta_f, phi_f, g_f, wfT_f, x, out);
}